// Round 1
// baseline (35889.590 us; speedup 1.0000x reference)
//
#include <hip/hip_runtime.h>
#include <hip/hip_bf16.h>
#include <stdint.h>
#include <stddef.h>

// STNRNN: leaky-integrated LSTM cell, B=32 T=2048 I=64 H=512, K=0.5.
// Design: 8 groups x 4 batches; 32 WGs/group, each WG owns 16 h-indices
// (64 gate rows). W_hh slice lives in LDS as bf16 (loaded once). Per step:
// stage h from global double-buffered state (agent-scope loads), matvec with
// k-split 16 + shfl_xor butterfly reduce, elementwise on 4 holder lanes/wave,
// agent-scope state stores, per-group per-step counter barrier (monotonic,
// device scope -> correct for any WG->XCD mapping).

#define T_STEPS 2048
#define H_DIM   512
#define I_DIM   64
#define B_TOT   32
#define NGROUP  8
#define WGS     32      // WGs per group
#define BPG     4       // batches per group
#define JW      16      // h-indices per WG
#define ROWS    64      // 4 gates * JW
#define NTH     256

// LDS strides chosen so row contributes 4*row to bank index (stride%32==4 in
// 4B words) and the interleaved k-split contributes 4*ks -> per-b128 read the
// 64 lanes tile all 32 banks exactly (8 starts x 4 consecutive banks).
#define WHH_LDS_STRIDE 520   // bf16 elems per row (1040 B, 16B aligned)
#define WIH_LDS_STRIDE 72    // bf16 elems per row (144 B)
#define H_LDS_STRIDE   516   // f32 elems per batch row (2064 B)
#define X_LDS_STRIDE   72    // f32 elems per batch row (288 B)

#define LDS_WHH_OFF 0
#define LDS_WIH_OFF (LDS_WHH_OFF + ROWS*WHH_LDS_STRIDE*2)   // 66560
#define LDS_H_OFF   (LDS_WIH_OFF + ROWS*WIH_LDS_STRIDE*2)   // 75776
#define LDS_X_OFF   (LDS_H_OFF + BPG*H_LDS_STRIDE*4)        // 84032
#define LDS_BS_OFF  (LDS_X_OFF + BPG*X_LDS_STRIDE*4)        // 85184
#define LDS_TOTAL   (LDS_BS_OFF + ROWS*4)                   // 85440 bytes

#define STATE_BYTES (2*B_TOT*1024*4)     // 262144: double-buffered [h|c] state
#define CNT_BYTES   (NGROUP*T_STEPS*4)   // 65536: per-group per-step counters

__device__ __forceinline__ float ld_agent(const float* p) {
  return __hip_atomic_load(const_cast<float*>(p), __ATOMIC_RELAXED,
                           __HIP_MEMORY_SCOPE_AGENT);
}
__device__ __forceinline__ void st_agent(float* p, float v) {
  __hip_atomic_store(p, v, __ATOMIC_RELAXED, __HIP_MEMORY_SCOPE_AGENT);
}
__device__ __forceinline__ float bf_lo(unsigned u) { return __uint_as_float(u << 16); }
__device__ __forceinline__ float bf_hi(unsigned u) { return __uint_as_float(u & 0xffff0000u); }
__device__ __forceinline__ float sigmoid_f(float x) { return 1.0f / (1.0f + __expf(-x)); }
__device__ __forceinline__ float tanh_f(float x)    { return 1.0f - 2.0f / (1.0f + __expf(2.0f * x)); }

extern "C" __global__ void __launch_bounds__(NTH, 1)
stnrnn_kernel(const float* __restrict__ x,
              const float* __restrict__ Wih,
              const float* __restrict__ Whh,
              const float* __restrict__ bih,
              const float* __restrict__ bhh,
              float* __restrict__ out,
              float* state,          // ws: [2][B_TOT][1024] (h|c)
              int*   cnt)            // ws: [NGROUP][T_STEPS]
{
  extern __shared__ char lds_raw[];
  __hip_bfloat16* lWhh = (__hip_bfloat16*)(lds_raw + LDS_WHH_OFF);
  __hip_bfloat16* lWih = (__hip_bfloat16*)(lds_raw + LDS_WIH_OFF);
  float* lh  = (float*)(lds_raw + LDS_H_OFF);
  float* lx  = (float*)(lds_raw + LDS_X_OFF);
  float* lbs = (float*)(lds_raw + LDS_BS_OFF);

  const int bid = blockIdx.x;
  const int g   = bid & 7;     // group (likely XCD under %8 round-robin)
  const int m   = bid >> 3;    // member within group, 0..31
  const int tid = threadIdx.x;
  const int jl  = tid >> 4;    // local h-index 0..15
  const int ks  = tid & 15;    // k-slice 0..15
  const int jg  = m * JW + jl; // global h-index 0..511
  const int bg0 = g * BPG;     // first global batch of this group

  // ---- one-time weight staging (fp32 -> bf16 RNE) ----
  for (int idx = tid; idx < ROWS * H_DIM; idx += NTH) {
    const int r = idx >> 9, k = idx & 511;          // r: gate-row in slice
    const int q = r >> 4, jj = r & 15;
    const int grow = q * H_DIM + m * JW + jj;
    lWhh[r * WHH_LDS_STRIDE + k] = __float2bfloat16(Whh[(size_t)grow * H_DIM + k]);
  }
  for (int idx = tid; idx < ROWS * I_DIM; idx += NTH) {
    const int r = idx >> 6, k = idx & 63;
    const int q = r >> 4, jj = r & 15;
    const int grow = q * H_DIM + m * JW + jj;
    lWih[r * WIH_LDS_STRIDE + k] = __float2bfloat16(Wih[(size_t)grow * I_DIM + k]);
  }
  if (tid < ROWS) {
    const int q = tid >> 4, jj = tid & 15;
    const int grow = q * H_DIM + m * JW + jj;
    lbs[tid] = bih[grow] + bhh[grow];
  }

  int* const mycnt = cnt + g * T_STEPS;

  for (int t = 0; t < T_STEPS; ++t) {
    const float* stin  = state + (size_t)(t & 1) * B_TOT * 1024;
    float*       stout = state + (size_t)((t + 1) & 1) * B_TOT * 1024;

    // ---- stage h-part of state into LDS (agent loads: bypass stale L1/L2) ----
    for (int idx = tid; idx < BPG * H_DIM; idx += NTH) {
      const int b = idx >> 9, k = idx & 511;
      lh[b * H_LDS_STRIDE + k] = ld_agent(stin + (size_t)(bg0 + b) * 1024 + k);
    }
    // stage x_t (read-only input, plain loads fine)
    {
      const int b = tid >> 6, i = tid & 63;   // NTH == BPG*I_DIM
      lx[b * X_LDS_STRIDE + i] = x[((size_t)(bg0 + b) * T_STEPS + t) * I_DIM + i];
    }
    // holders prefetch c (c-part of state)
    float cc[4] = {0.f, 0.f, 0.f, 0.f};
    if (ks == 0) {
      #pragma unroll
      for (int b = 0; b < 4; ++b)
        cc[b] = ld_agent(stin + (size_t)(bg0 + b) * 1024 + H_DIM + jg);
    }
    __syncthreads();

    float acc[4][4] = {};   // [gate q][batch b]

    // ---- x @ W_ih.T part: this thread handles k = ks*4 .. ks*4+3 ----
    {
      float4 xv[4];
      #pragma unroll
      for (int b = 0; b < 4; ++b)
        xv[b] = *(const float4*)(lx + b * X_LDS_STRIDE + ks * 4);
      #pragma unroll
      for (int q = 0; q < 4; ++q) {
        const uint2 u = *(const uint2*)(lWih + (q * JW + jl) * WIH_LDS_STRIDE + ks * 4);
        const float w0 = bf_lo(u.x), w1 = bf_hi(u.x);
        const float w2 = bf_lo(u.y), w3 = bf_hi(u.y);
        #pragma unroll
        for (int b = 0; b < 4; ++b)
          acc[q][b] += w0 * xv[b].x + w1 * xv[b].y + w2 * xv[b].z + w3 * xv[b].w;
      }
    }

    // ---- h @ W_hh.T part: interleaved k-split, k = ks*8 + mm*128 .. +7 ----
    #pragma unroll
    for (int mm = 0; mm < 4; ++mm) {
      const int kbase = ks * 8 + mm * 128;
      float hv[4][8];
      #pragma unroll
      for (int b = 0; b < 4; ++b) {
        const float4 a = *(const float4*)(lh + b * H_LDS_STRIDE + kbase);
        const float4 c = *(const float4*)(lh + b * H_LDS_STRIDE + kbase + 4);
        hv[b][0] = a.x; hv[b][1] = a.y; hv[b][2] = a.z; hv[b][3] = a.w;
        hv[b][4] = c.x; hv[b][5] = c.y; hv[b][6] = c.z; hv[b][7] = c.w;
      }
      #pragma unroll
      for (int q = 0; q < 4; ++q) {
        const uint4 u = *(const uint4*)(lWhh + (q * JW + jl) * WHH_LDS_STRIDE + kbase);
        float wv[8];
        wv[0] = bf_lo(u.x); wv[1] = bf_hi(u.x);
        wv[2] = bf_lo(u.y); wv[3] = bf_hi(u.y);
        wv[4] = bf_lo(u.z); wv[5] = bf_hi(u.z);
        wv[6] = bf_lo(u.w); wv[7] = bf_hi(u.w);
        #pragma unroll
        for (int b = 0; b < 4; ++b) {
          float s = acc[q][b];
          #pragma unroll
          for (int e = 0; e < 8; ++e) s += wv[e] * hv[b][e];
          acc[q][b] = s;
        }
      }
    }

    // ---- butterfly reduce across the 16 k-slice lanes ----
    #pragma unroll
    for (int mask = 1; mask <= 8; mask <<= 1) {
      #pragma unroll
      for (int q = 0; q < 4; ++q)
        #pragma unroll
        for (int b = 0; b < 4; ++b)
          acc[q][b] += __shfl_xor(acc[q][b], mask, 64);
    }

    // ---- elementwise cell update on holder lanes (ks==0) ----
    if (ks == 0) {
      #pragma unroll
      for (int b = 0; b < 4; ++b) {
        const float gi = acc[0][b] + lbs[jl];
        const float gf = acc[1][b] + lbs[JW + jl];
        const float gg = acc[2][b] + lbs[2 * JW + jl];
        const float go = acc[3][b] + lbs[3 * JW + jl];
        const float si = sigmoid_f(gi);
        const float sf = sigmoid_f(gf);
        const float so = sigmoid_f(go);
        const float cn = sf * cc[b] + si * tanh_f(gg);
        const float hn = so * tanh_f(cn);
        const float hold = lh[b * H_LDS_STRIDE + jg];
        const float hs = 0.5f * (hold + hn);     // K = 0.5 leaky blend
        const float cs = 0.5f * (cc[b] + cn);
        st_agent(stout + (size_t)(bg0 + b) * 1024 + jg, hs);
        st_agent(stout + (size_t)(bg0 + b) * 1024 + H_DIM + jg, cs);
        out[((size_t)(bg0 + b) * T_STEPS + t) * H_DIM + jg] = hs;
        if (t == T_STEPS - 1) {
          const size_t base = (size_t)B_TOT * T_STEPS * H_DIM;
          out[base + (size_t)(bg0 + b) * 1024 + jg] = hs;
          out[base + (size_t)(bg0 + b) * 1024 + H_DIM + jg] = cs;
        }
      }
    }

    // ---- per-group barrier: monotonic per-step counter (device scope) ----
    __syncthreads();   // drains vmcnt: all waves' stores visible at L2
    if (tid == 0) {
      __threadfence();
      atomicAdd(mycnt + t, 1);
      while (__hip_atomic_load(mycnt + t, __ATOMIC_RELAXED,
                               __HIP_MEMORY_SCOPE_AGENT) < WGS)
        __builtin_amdgcn_s_sleep(1);
      __threadfence();
    }
    __syncthreads();
  }
}

extern "C" void kernel_launch(void* const* d_in, const int* in_sizes, int n_in,
                              void* d_out, int out_size, void* d_ws, size_t ws_size,
                              hipStream_t stream) {
  (void)in_sizes; (void)n_in; (void)out_size; (void)ws_size;
  const float* x   = (const float*)d_in[0];
  const float* Wih = (const float*)d_in[1];
  const float* Whh = (const float*)d_in[2];
  const float* bih = (const float*)d_in[3];
  const float* bhh = (const float*)d_in[4];
  float* out   = (float*)d_out;
  float* state = (float*)d_ws;
  int*   cnt   = (int*)((char*)d_ws + STATE_BYTES);

  // zero initial state (h0 = 0) and barrier counters
  hipMemsetAsync(d_ws, 0, STATE_BYTES + CNT_BYTES, stream);

  hipFuncSetAttribute(reinterpret_cast<const void*>(&stnrnn_kernel),
                      hipFuncAttributeMaxDynamicSharedMemorySize, LDS_TOTAL);

  hipLaunchKernelGGL(stnrnn_kernel, dim3(NGROUP * WGS), dim3(NTH), LDS_TOTAL,
                     stream, x, Wih, Whh, bih, bhh, out, state, cnt);
}

// Round 2
// 21083.324 us; speedup vs baseline: 1.7023x; 1.7023x over previous
//
#include <hip/hip_runtime.h>
#include <hip/hip_bf16.h>
#include <stdint.h>
#include <stddef.h>

// STNRNN: leaky-integrated LSTM cell, B=32 T=2048 I=64 H=512, K=0.5.
// 8 independent groups x 4 batches; 32 WGs/group, each WG owns 16 h-indices
// (64 gate rows). W_hh slice in LDS as bf16 (loaded once). Per step: stage h
// from global double-buffered h-state (agent-scope sc0sc1 loads -> MALL
// coherent), bf16xf32 matvec with k-split 16 + shfl_xor butterfly reduce,
// elementwise on holder lanes (c stays in registers!), agent-scope h stores,
// per-group per-step monotonic counter barrier.
//
// Round-2 changes vs round-1 (which was 17.5us/step, VALUBusy 11.6%):
//  - REMOVED __threadfence() (emitted buffer_wbl2/inv = per-XCD L2 flush,
//    2x per WG per step = the dominant serial cost). Replaced with
//    s_waitcnt vmcnt(0) + compiler barriers: all exchanged data is sc0sc1
//    (bypasses L1/L2) so no cache maintenance is needed, only HW ordering.
//  - c state lives in holder-lane registers across all 2048 steps (no global
//    c round-trip; state buffers now h-only).
//  - lh LDS layout swizzled into 12-word groups: kills the 4-way bank
//    conflict on the h float4 reads (16 ks lanes now start on 8 distinct
//    4-bank groups covering all 32 banks; 2-way alias is free).

#define T_STEPS 2048
#define H_DIM   512
#define I_DIM   64
#define B_TOT   32
#define NGROUP  8
#define WGS     32      // WGs per group
#define BPG     4       // batches per group
#define JW      16      // h-indices per WG
#define ROWS    64      // 4 gates * JW
#define NTH     256

#define WHH_LDS_STRIDE 520   // bf16 elems per row (1040 B, 16B aligned)
#define WIH_LDS_STRIDE 72    // bf16 elems per row (144 B)
#define LH_GROUP       12    // words per 8-float group (48 B, 16B aligned)
#define LH_B           768   // words per batch row (64 groups * 12)
#define X_LDS_STRIDE   72    // f32 elems per batch row (288 B)

#define LDS_WHH_OFF 0
#define LDS_WIH_OFF (LDS_WHH_OFF + ROWS*WHH_LDS_STRIDE*2)   // 66560
#define LDS_H_OFF   (LDS_WIH_OFF + ROWS*WIH_LDS_STRIDE*2)   // 75776
#define LDS_X_OFF   (LDS_H_OFF + BPG*LH_B*4)                // 88064
#define LDS_BS_OFF  (LDS_X_OFF + BPG*X_LDS_STRIDE*4)        // 89216
#define LDS_TOTAL   (LDS_BS_OFF + ROWS*4)                   // 89472 bytes

#define STATE_BYTES (2*B_TOT*H_DIM*4)    // 131072: double-buffered h state
#define CNT_BYTES   (NGROUP*T_STEPS*4)   // 65536: per-group per-step counters

__device__ __forceinline__ float ld_agent(const float* p) {
  return __hip_atomic_load(const_cast<float*>(p), __ATOMIC_RELAXED,
                           __HIP_MEMORY_SCOPE_AGENT);
}
__device__ __forceinline__ void st_agent(float* p, float v) {
  __hip_atomic_store(p, v, __ATOMIC_RELAXED, __HIP_MEMORY_SCOPE_AGENT);
}
__device__ __forceinline__ float bf_lo(unsigned u) { return __uint_as_float(u << 16); }
__device__ __forceinline__ float bf_hi(unsigned u) { return __uint_as_float(u & 0xffff0000u); }
__device__ __forceinline__ float sigmoid_f(float x) { return 1.0f / (1.0f + __expf(-x)); }
__device__ __forceinline__ float tanh_f(float x)    { return 1.0f - 2.0f / (1.0f + __expf(2.0f * x)); }
// swizzled word index for staged h: 8-float groups padded to 12 words
__device__ __forceinline__ int lhw(int b, int k) {
  return b * LH_B + ((k >> 3) * LH_GROUP) + (k & 7);
}

extern "C" __global__ void __launch_bounds__(NTH, 1)
stnrnn_kernel(const float* __restrict__ x,
              const float* __restrict__ Wih,
              const float* __restrict__ Whh,
              const float* __restrict__ bih,
              const float* __restrict__ bhh,
              float* __restrict__ out,
              float* state,          // ws: [2][B_TOT][H_DIM] (h only)
              int*   cnt)            // ws: [NGROUP][T_STEPS]
{
  extern __shared__ char lds_raw[];
  __hip_bfloat16* lWhh = (__hip_bfloat16*)(lds_raw + LDS_WHH_OFF);
  __hip_bfloat16* lWih = (__hip_bfloat16*)(lds_raw + LDS_WIH_OFF);
  float* lh  = (float*)(lds_raw + LDS_H_OFF);
  float* lx  = (float*)(lds_raw + LDS_X_OFF);
  float* lbs = (float*)(lds_raw + LDS_BS_OFF);

  const int bid = blockIdx.x;
  const int g   = bid & 7;     // group
  const int m   = bid >> 3;    // member within group, 0..31
  const int tid = threadIdx.x;
  const int jl  = tid >> 4;    // local h-index 0..15
  const int ks  = tid & 15;    // k-slice 0..15
  const int jg  = m * JW + jl; // global h-index 0..511
  const int bg0 = g * BPG;     // first global batch of this group

  // ---- one-time weight staging (fp32 -> bf16 RNE) ----
  for (int idx = tid; idx < ROWS * H_DIM; idx += NTH) {
    const int r = idx >> 9, k = idx & 511;
    const int q = r >> 4, jj = r & 15;
    const int grow = q * H_DIM + m * JW + jj;
    lWhh[r * WHH_LDS_STRIDE + k] = __float2bfloat16(Whh[(size_t)grow * H_DIM + k]);
  }
  for (int idx = tid; idx < ROWS * I_DIM; idx += NTH) {
    const int r = idx >> 6, k = idx & 63;
    const int q = r >> 4, jj = r & 15;
    const int grow = q * H_DIM + m * JW + jj;
    lWih[r * WIH_LDS_STRIDE + k] = __float2bfloat16(Wih[(size_t)grow * I_DIM + k]);
  }
  if (tid < ROWS) {
    const int q = tid >> 4, jj = tid & 15;
    const int grow = q * H_DIM + m * JW + jj;
    lbs[tid] = bih[grow] + bhh[grow];
  }

  int* const mycnt = cnt + g * T_STEPS;
  float creg[4] = {0.f, 0.f, 0.f, 0.f};   // blended c, holder lanes only

  for (int t = 0; t < T_STEPS; ++t) {
    const float* stin  = state + (size_t)(t & 1) * B_TOT * H_DIM;
    float*       stout = state + (size_t)((t + 1) & 1) * B_TOT * H_DIM;

    // ---- stage h state into LDS (sc0sc1 loads: coherent via MALL) ----
    #pragma unroll
    for (int it = 0; it < (BPG * H_DIM) / NTH; ++it) {
      const int idx = it * NTH + tid;
      const int b = idx >> 9, k = idx & 511;
      lh[lhw(b, k)] = ld_agent(stin + (size_t)(bg0 + b) * H_DIM + k);
    }
    // stage x_t (read-only input, plain loads fine)
    {
      const int b = tid >> 6, i = tid & 63;   // NTH == BPG*I_DIM
      lx[b * X_LDS_STRIDE + i] = x[((size_t)(bg0 + b) * T_STEPS + t) * I_DIM + i];
    }
    __syncthreads();

    float acc[4][4] = {};   // [gate q][batch b]

    // ---- x @ W_ih.T part: k = ks*4 .. ks*4+3 ----
    {
      float4 xv[4];
      #pragma unroll
      for (int b = 0; b < 4; ++b)
        xv[b] = *(const float4*)(lx + b * X_LDS_STRIDE + ks * 4);
      #pragma unroll
      for (int q = 0; q < 4; ++q) {
        const uint2 u = *(const uint2*)(lWih + (q * JW + jl) * WIH_LDS_STRIDE + ks * 4);
        const float w0 = bf_lo(u.x), w1 = bf_hi(u.x);
        const float w2 = bf_lo(u.y), w3 = bf_hi(u.y);
        #pragma unroll
        for (int b = 0; b < 4; ++b)
          acc[q][b] += w0 * xv[b].x + w1 * xv[b].y + w2 * xv[b].z + w3 * xv[b].w;
      }
    }

    // ---- h @ W_hh.T part: k = ks*8 + mm*128 .. +7 ----
    #pragma unroll
    for (int mm = 0; mm < 4; ++mm) {
      const int kbase = ks * 8 + mm * 128;
      const int hw = (ks + mm * 16) * LH_GROUP;   // swizzled word offset of kbase
      float hv[4][8];
      #pragma unroll
      for (int b = 0; b < 4; ++b) {
        const float4 a = *(const float4*)(lh + b * LH_B + hw);
        const float4 c = *(const float4*)(lh + b * LH_B + hw + 4);
        hv[b][0] = a.x; hv[b][1] = a.y; hv[b][2] = a.z; hv[b][3] = a.w;
        hv[b][4] = c.x; hv[b][5] = c.y; hv[b][6] = c.z; hv[b][7] = c.w;
      }
      #pragma unroll
      for (int q = 0; q < 4; ++q) {
        const uint4 u = *(const uint4*)(lWhh + (q * JW + jl) * WHH_LDS_STRIDE + kbase);
        float wv[8];
        wv[0] = bf_lo(u.x); wv[1] = bf_hi(u.x);
        wv[2] = bf_lo(u.y); wv[3] = bf_hi(u.y);
        wv[4] = bf_lo(u.z); wv[5] = bf_hi(u.z);
        wv[6] = bf_lo(u.w); wv[7] = bf_hi(u.w);
        #pragma unroll
        for (int b = 0; b < 4; ++b) {
          float s = acc[q][b];
          #pragma unroll
          for (int e = 0; e < 8; ++e) s += wv[e] * hv[b][e];
          acc[q][b] = s;
        }
      }
    }

    // ---- butterfly reduce across the 16 k-slice lanes ----
    #pragma unroll
    for (int mask = 1; mask <= 8; mask <<= 1) {
      #pragma unroll
      for (int q = 0; q < 4; ++q)
        #pragma unroll
        for (int b = 0; b < 4; ++b)
          acc[q][b] += __shfl_xor(acc[q][b], mask, 64);
    }

    // ---- elementwise cell update on holder lanes (ks==0); c in registers ----
    if (ks == 0) {
      #pragma unroll
      for (int b = 0; b < 4; ++b) {
        const float gi = acc[0][b] + lbs[jl];
        const float gf = acc[1][b] + lbs[JW + jl];
        const float gg = acc[2][b] + lbs[2 * JW + jl];
        const float go = acc[3][b] + lbs[3 * JW + jl];
        const float si = sigmoid_f(gi);
        const float sf = sigmoid_f(gf);
        const float so = sigmoid_f(go);
        const float cn = sf * creg[b] + si * tanh_f(gg);
        const float hn = so * tanh_f(cn);
        const float hold = lh[lhw(b, jg)];
        const float hs = 0.5f * (hold + hn);     // K = 0.5 leaky blend
        const float cs = 0.5f * (creg[b] + cn);
        creg[b] = cs;
        st_agent(stout + (size_t)(bg0 + b) * H_DIM + jg, hs);
        out[((size_t)(bg0 + b) * T_STEPS + t) * H_DIM + jg] = hs;
        if (t == T_STEPS - 1) {
          const size_t base = (size_t)B_TOT * T_STEPS * H_DIM;
          out[base + (size_t)(bg0 + b) * 1024 + jg] = hs;
          out[base + (size_t)(bg0 + b) * 1024 + H_DIM + jg] = cs;
        }
      }
    }

    // ---- per-group barrier: monotonic per-step counter, NO cache flushes ----
    // __syncthreads() makes each wave drain vmcnt before s_barrier, so all
    // waves' sc1 stores are at the coherence point when tid 0 announces.
    __syncthreads();
    if (tid == 0) {
      asm volatile("s_waitcnt vmcnt(0)" ::: "memory");  // belt: wave0 stores
      __hip_atomic_fetch_add(mycnt + t, 1, __ATOMIC_RELAXED,
                             __HIP_MEMORY_SCOPE_AGENT);
      while (__hip_atomic_load(mycnt + t, __ATOMIC_RELAXED,
                               __HIP_MEMORY_SCOPE_AGENT) < WGS)
        __builtin_amdgcn_s_sleep(1);
      asm volatile("" ::: "memory");                    // compiler fence only
    }
    __syncthreads();
  }
}

extern "C" void kernel_launch(void* const* d_in, const int* in_sizes, int n_in,
                              void* d_out, int out_size, void* d_ws, size_t ws_size,
                              hipStream_t stream) {
  (void)in_sizes; (void)n_in; (void)out_size; (void)ws_size;
  const float* x   = (const float*)d_in[0];
  const float* Wih = (const float*)d_in[1];
  const float* Whh = (const float*)d_in[2];
  const float* bih = (const float*)d_in[3];
  const float* bhh = (const float*)d_in[4];
  float* out   = (float*)d_out;
  float* state = (float*)d_ws;
  int*   cnt   = (int*)((char*)d_ws + STATE_BYTES);

  // zero initial state (h0 = 0) and barrier counters
  hipMemsetAsync(d_ws, 0, STATE_BYTES + CNT_BYTES, stream);

  hipFuncSetAttribute(reinterpret_cast<const void*>(&stnrnn_kernel),
                      hipFuncAttributeMaxDynamicSharedMemorySize, LDS_TOTAL);

  hipLaunchKernelGGL(stnrnn_kernel, dim3(NGROUP * WGS), dim3(NTH), LDS_TOTAL,
                     stream, x, Wih, Whh, bih, bhh, out, state, cnt);
}

// Round 3
// 11248.908 us; speedup vs baseline: 3.1905x; 1.8743x over previous
//
#include <hip/hip_runtime.h>
#include <hip/hip_bf16.h>
#include <stdint.h>
#include <stddef.h>

// STNRNN round 3: MFMA matvec, zero LDS, W resident in VGPRs.
// 16 groups x 2 batches; 16 WGs/group, each WG owns 32 j (128 gate rows).
// Per wave: 2 row-tiles (16x16) x 16 k-tiles of mfma_f32_16x16x32_bf16.
// A (W) fragments: loaded once into VGPRs (tile row r = jj*4+q so each
// lane's 4 C regs = the 4 gates of one (j,b) -> in-lane elementwise).
// h state exchanged as bf16 hi+res pairs (split-bf16 ~= f32 operand
// precision); blend h/c stay in f32 regs of the producing lane.
// B fragments loaded straight from MALL (global_load_dwordx4 sc0 sc1),
// issue-all then vmcnt(20)/vmcnt(0) phased consumption.

#define T_STEPS 2048
#define H_DIM   512
#define I_DIM   64
#define B_TOT   32
#define NGROUP  16
#define WGS     16      // WGs per group
#define BPG     2       // batches per group
#define NTH     256

typedef float f32x4 __attribute__((ext_vector_type(4)));
typedef short s16x8 __attribute__((ext_vector_type(8)));

#define STATE_HALF (B_TOT*H_DIM)                  // ushorts per buffer
#define SHI_BYTES  (2*STATE_HALF*2)               // 65536 (double buffered)
#define SRES_OFF   SHI_BYTES
#define CNT_OFF    (SRES_OFF + SHI_BYTES)         // 131072
#define WS_BYTES   (CNT_OFF + NGROUP*T_STEPS*4)   // 262144

__device__ __forceinline__ unsigned short bf16_rne(float f) {
  __hip_bfloat16 b = __float2bfloat16(f);
  return __builtin_bit_cast(unsigned short, b);
}
__device__ __forceinline__ float bf16_to_f(unsigned short u) {
  return __uint_as_float(((unsigned)u) << 16);
}
__device__ __forceinline__ f32x4 ld_agent_b128(const void* p) {
  f32x4 r;
  asm volatile("global_load_dwordx4 %0, %1, off sc0 sc1" : "=v"(r) : "v"(p));
  return r;
}
__device__ __forceinline__ void st_agent_u16(void* p, unsigned v) {
  asm volatile("global_store_short %0, %1, off sc0 sc1" :: "v"(p), "v"(v) : "memory");
}
__device__ __forceinline__ s16x8 make_frag(const float* p) {
  const float4 a = *(const float4*)p;
  const float4 b = *(const float4*)(p + 4);
  s16x8 f;
  f[0] = (short)bf16_rne(a.x); f[1] = (short)bf16_rne(a.y);
  f[2] = (short)bf16_rne(a.z); f[3] = (short)bf16_rne(a.w);
  f[4] = (short)bf16_rne(b.x); f[5] = (short)bf16_rne(b.y);
  f[6] = (short)bf16_rne(b.z); f[7] = (short)bf16_rne(b.w);
  return f;
}
// split 8 floats into bf16 hi + bf16 residual fragments
__device__ __forceinline__ void split8(const float4& a, const float4& b,
                                       s16x8& hi, s16x8& lo) {
  float v[8] = {a.x, a.y, a.z, a.w, b.x, b.y, b.z, b.w};
  #pragma unroll
  for (int e = 0; e < 8; ++e) {
    const unsigned short h = bf16_rne(v[e]);
    hi[e] = (short)h;
    lo[e] = (short)bf16_rne(v[e] - bf16_to_f(h));
  }
}
__device__ __forceinline__ float sigmoid_f(float v) { return 1.0f / (1.0f + __expf(-v)); }
__device__ __forceinline__ float tanh_f(float v)    { return 1.0f - 2.0f / (1.0f + __expf(2.0f * v)); }

extern "C" __global__ void __launch_bounds__(NTH, 1)
stnrnn_kernel(const float* __restrict__ x,
              const float* __restrict__ Wih,
              const float* __restrict__ Whh,
              const float* __restrict__ bih,
              const float* __restrict__ bhh,
              float* __restrict__ out,
              unsigned short* sHi,   // ws: [2][B_TOT][H_DIM] bf16 hi
              unsigned short* sRes,  // ws: [2][B_TOT][H_DIM] bf16 residual
              int* cnt)              // ws: [NGROUP][T_STEPS]
{
  const int bid = blockIdx.x;
  const int g   = bid & 15;     // group
  const int m   = bid >> 4;     // member 0..15 -> j slice
  const int tid = threadIdx.x;
  const int w   = tid >> 6;     // wave 0..3
  const int l   = tid & 63;
  const int p   = l >> 4;       // k-group / C row-quad
  const int c16 = l & 15;       // A row (load) / C col (readout)
  const int bb  = c16 & 1;      // batch for B-fragment duty
  const int bg0 = g * BPG;
  const int jj  = c16 >> 2, q = c16 & 3;  // tile row r = jj*4 + q

  // ---- one-time A fragments (W in VGPRs, bf16) ----
  s16x8 ahh[2][16];
  s16x8 aih[2][2];
  #pragma unroll
  for (int rt = 0; rt < 2; ++rt) {
    const int jbase = m * 32 + (w * 2 + rt) * 4;
    const int grow  = q * H_DIM + jbase + jj;
    #pragma unroll
    for (int kt = 0; kt < 16; ++kt)
      ahh[rt][kt] = make_frag(Whh + (size_t)grow * H_DIM + kt * 32 + p * 8);
    #pragma unroll
    for (int kt = 0; kt < 2; ++kt)
      aih[rt][kt] = make_frag(Wih + (size_t)grow * I_DIM + kt * 32 + p * 8);
  }
  // per-lane readout constants: j indices, biases
  float bias[2][4];
  #pragma unroll
  for (int rt = 0; rt < 2; ++rt) {
    const int jme = m * 32 + (w * 2 + rt) * 4 + p;
    #pragma unroll
    for (int qq = 0; qq < 4; ++qq)
      bias[rt][qq] = bih[qq * H_DIM + jme] + bhh[qq * H_DIM + jme];
  }
  const int  jme[2]  = {m * 32 + (w * 2) * 4 + p, m * 32 + (w * 2 + 1) * 4 + p};
  const int  bme     = bg0 + c16;          // valid only when c16 < BPG
  const bool active  = (c16 < BPG);

  float hreg[2] = {0.f, 0.f}, creg[2] = {0.f, 0.f};
  int* const mycnt = cnt + g * T_STEPS;

  for (int t = 0; t < T_STEPS; ++t) {
    // ---- x for this step (plain cached loads; consumed after vmcnt(0)) ----
    const float* xp = x + ((size_t)(bg0 + bb) * T_STEPS + t) * I_DIM + p * 8;
    const float4 xv0a = *(const float4*)(xp);
    const float4 xv0b = *(const float4*)(xp + 4);
    const float4 xv1a = *(const float4*)(xp + 32);
    const float4 xv1b = *(const float4*)(xp + 32 + 4);

    // ---- issue all 32 B-fragment loads (MALL-coherent) ----
    const unsigned short* hiB = sHi  + (size_t)(t & 1) * STATE_HALF;
    const unsigned short* reB = sRes + (size_t)(t & 1) * STATE_HALF;
    const size_t bOff = (size_t)(bg0 + bb) * H_DIM + p * 8;
    f32x4 bhi[16], bres[16];
    #pragma unroll
    for (int kt = 0; kt < 16; ++kt) {
      bhi[kt]  = ld_agent_b128(hiB + bOff + kt * 32);
      bres[kt] = ld_agent_b128(reB + bOff + kt * 32);
    }

    f32x4 acc[2] = {{0.f, 0.f, 0.f, 0.f}, {0.f, 0.f, 0.f, 0.f}};

    // phase 1: first 16 loads (kt 0..7) done when <=20 remain of (mine+any)
    asm volatile("s_waitcnt vmcnt(20)" ::: "memory");
    __builtin_amdgcn_sched_barrier(0);
    #pragma unroll
    for (int kt = 0; kt < 8; ++kt) {
      const s16x8 bh = __builtin_bit_cast(s16x8, bhi[kt]);
      const s16x8 br = __builtin_bit_cast(s16x8, bres[kt]);
      acc[0] = __builtin_amdgcn_mfma_f32_16x16x32_bf16(ahh[0][kt], bh, acc[0], 0, 0, 0);
      acc[1] = __builtin_amdgcn_mfma_f32_16x16x32_bf16(ahh[1][kt], bh, acc[1], 0, 0, 0);
      acc[0] = __builtin_amdgcn_mfma_f32_16x16x32_bf16(ahh[0][kt], br, acc[0], 0, 0, 0);
      acc[1] = __builtin_amdgcn_mfma_f32_16x16x32_bf16(ahh[1][kt], br, acc[1], 0, 0, 0);
    }
    // phase 2: everything in flight done
    asm volatile("s_waitcnt vmcnt(0)" ::: "memory");
    __builtin_amdgcn_sched_barrier(0);
    #pragma unroll
    for (int kt = 8; kt < 16; ++kt) {
      const s16x8 bh = __builtin_bit_cast(s16x8, bhi[kt]);
      const s16x8 br = __builtin_bit_cast(s16x8, bres[kt]);
      acc[0] = __builtin_amdgcn_mfma_f32_16x16x32_bf16(ahh[0][kt], bh, acc[0], 0, 0, 0);
      acc[1] = __builtin_amdgcn_mfma_f32_16x16x32_bf16(ahh[1][kt], bh, acc[1], 0, 0, 0);
      acc[0] = __builtin_amdgcn_mfma_f32_16x16x32_bf16(ahh[0][kt], br, acc[0], 0, 0, 0);
      acc[1] = __builtin_amdgcn_mfma_f32_16x16x32_bf16(ahh[1][kt], br, acc[1], 0, 0, 0);
    }
    // x part (K=64): split to hi/res fragments, 8 more MFMAs
    {
      s16x8 xh0, xr0, xh1, xr1;
      split8(xv0a, xv0b, xh0, xr0);
      split8(xv1a, xv1b, xh1, xr1);
      acc[0] = __builtin_amdgcn_mfma_f32_16x16x32_bf16(aih[0][0], xh0, acc[0], 0, 0, 0);
      acc[1] = __builtin_amdgcn_mfma_f32_16x16x32_bf16(aih[1][0], xh0, acc[1], 0, 0, 0);
      acc[0] = __builtin_amdgcn_mfma_f32_16x16x32_bf16(aih[0][0], xr0, acc[0], 0, 0, 0);
      acc[1] = __builtin_amdgcn_mfma_f32_16x16x32_bf16(aih[1][0], xr0, acc[1], 0, 0, 0);
      acc[0] = __builtin_amdgcn_mfma_f32_16x16x32_bf16(aih[0][1], xh1, acc[0], 0, 0, 0);
      acc[1] = __builtin_amdgcn_mfma_f32_16x16x32_bf16(aih[1][1], xh1, acc[1], 0, 0, 0);
      acc[0] = __builtin_amdgcn_mfma_f32_16x16x32_bf16(aih[0][1], xr1, acc[0], 0, 0, 0);
      acc[1] = __builtin_amdgcn_mfma_f32_16x16x32_bf16(aih[1][1], xr1, acc[1], 0, 0, 0);
    }

    // ---- in-lane elementwise cell + blend + stores (16 lanes/wave) ----
    if (active) {
      unsigned short* oHi = sHi  + (size_t)((t + 1) & 1) * STATE_HALF + (size_t)bme * H_DIM;
      unsigned short* oRe = sRes + (size_t)((t + 1) & 1) * STATE_HALF + (size_t)bme * H_DIM;
      #pragma unroll
      for (int rt = 0; rt < 2; ++rt) {
        const float gi = acc[rt][0] + bias[rt][0];
        const float gf = acc[rt][1] + bias[rt][1];
        const float gg = acc[rt][2] + bias[rt][2];
        const float go = acc[rt][3] + bias[rt][3];
        const float si = sigmoid_f(gi);
        const float sf = sigmoid_f(gf);
        const float so = sigmoid_f(go);
        const float cn = sf * creg[rt] + si * tanh_f(gg);
        const float hn = so * tanh_f(cn);
        const float hs = 0.5f * (hreg[rt] + hn);   // K = 0.5 leaky blend
        const float cs = 0.5f * (creg[rt] + cn);
        hreg[rt] = hs; creg[rt] = cs;
        out[((size_t)bme * T_STEPS + t) * H_DIM + jme[rt]] = hs;
        const unsigned short h16 = bf16_rne(hs);
        const unsigned short r16 = bf16_rne(hs - bf16_to_f(h16));
        st_agent_u16(oHi + jme[rt], h16);
        st_agent_u16(oRe + jme[rt], r16);
        if (t == T_STEPS - 1) {
          const size_t base2 = (size_t)B_TOT * T_STEPS * H_DIM;
          out[base2 + (size_t)bme * 1024 + jme[rt]] = hs;
          out[base2 + (size_t)bme * 1024 + H_DIM + jme[rt]] = cs;
        }
      }
    }

    // ---- per-group barrier (skip after last step) ----
    if (t < T_STEPS - 1) {
      asm volatile("s_waitcnt vmcnt(0)" ::: "memory");  // asm stores drained
      __syncthreads();
      if (tid == 0) {
        __hip_atomic_fetch_add(mycnt + t, 1, __ATOMIC_RELAXED,
                               __HIP_MEMORY_SCOPE_AGENT);
        while (__hip_atomic_load(mycnt + t, __ATOMIC_RELAXED,
                                 __HIP_MEMORY_SCOPE_AGENT) < WGS)
          __builtin_amdgcn_s_sleep(1);
        asm volatile("" ::: "memory");
      }
      __syncthreads();
    }
  }
}

extern "C" void kernel_launch(void* const* d_in, const int* in_sizes, int n_in,
                              void* d_out, int out_size, void* d_ws, size_t ws_size,
                              hipStream_t stream) {
  (void)in_sizes; (void)n_in; (void)out_size; (void)ws_size;
  const float* x   = (const float*)d_in[0];
  const float* Wih = (const float*)d_in[1];
  const float* Whh = (const float*)d_in[2];
  const float* bih = (const float*)d_in[3];
  const float* bhh = (const float*)d_in[4];
  float* out = (float*)d_out;
  unsigned short* sHi  = (unsigned short*)d_ws;
  unsigned short* sRes = (unsigned short*)((char*)d_ws + SRES_OFF);
  int* cnt = (int*)((char*)d_ws + CNT_OFF);

  // zero h0 state (both buffers) and barrier counters, every launch
  hipMemsetAsync(d_ws, 0, WS_BYTES, stream);

  hipLaunchKernelGGL(stnrnn_kernel, dim3(NGROUP * WGS), dim3(NTH), 0,
                     stream, x, Wih, Whh, bih, bhh, out, sHi, sRes, cnt);
}